// Round 2
// 431.238 us; speedup vs baseline: 1.1408x; 1.1408x over previous
//
#include <hip/hip_runtime.h>

// Trellis-walk LUT dequant: out[r][c] = 0.011 * sign_l[r] * sign_r[c] *
//   lut[ walks[(r/16)*512 + c/16][ ((r%16)*16 + (c%16)) >> 1 ] ][ c & 1 ]
//
// R3 restructure (TA-transaction-bound per R0-R2 counters: VALUBusy 2%,
// hbm 29% peak, FETCH 2x walks):
//   - Block = 16 consecutive tiles (one tile-row segment, 8 KB of walks).
//   - Phase 1: stage walks into LDS with fully-coalesced 16B/lane loads
//     (each HBM line fetched exactly once -> kills the 2x over-fetch
//     that came from sibling rows landing on different XCDs).
//   - Phase 2: each thread produces 4 lane-interleaved float4s so every
//     store instruction is wave-contiguous (full 64B lines, 16 tx/instr
//     instead of 64 partial-line tx). Walk indices come from LDS
//     (ds_read_b64: 16 bank-pairs x 4 lanes = all 32 banks busy, optimal).
//   - Only the 8 random LUT gathers/thread remain divergent (irreducible).
//   - Nontemporal on walks/out keeps the 512 KB LUT L2-resident.
//   - R4 fix: __builtin_nontemporal_* requires clang ext_vector types,
//     not HIP_vector_type classes -> reinterpret through int4v/float4v.
//
// Device layout facts (established R0-R2):
//   - walks is INT32 on device; out is FLOAT32.

typedef int   int4v   __attribute__((ext_vector_type(4)));
typedef float float4v __attribute__((ext_vector_type(4)));

__global__ __launch_bounds__(256) void trellis_dequant(
    const int* __restrict__ walks,      // (262144, 128) int32, values < 2^16
    const float* __restrict__ lut,      // (65536, 2)
    const float* __restrict__ sign_l,   // (8192,)
    const float* __restrict__ sign_r,   // (8192,)
    float* __restrict__ out)            // (8192, 8192) float32
{
    __shared__ int4v wlds4[512];        // 16 tiles x 128 ints = 8 KB

    const int b   = blockIdx.x;
    const int T0  = b << 4;             // first linear tile of this block
    const int tr  = T0 >> 9;            // tile row
    const int tc0 = T0 & 511;           // first tile col

    // ---- Phase 1: coalesced stage of 16 tiles' walks into LDS ----
    const int4v* gw = (const int4v*)(walks + (size_t)T0 * 128);
    const int t = threadIdx.x;
    wlds4[t]       = __builtin_nontemporal_load(gw + t);
    wlds4[t + 256] = __builtin_nontemporal_load(gw + t + 256);
    __syncthreads();

    // ---- Phase 2: 4 lane-interleaved float4s per thread ----
    const int2*   wlds2 = (const int2*)wlds4;
    const float2* lut2  = (const float2*)lut;

    const int l = threadIdx.x & 63;     // lane
    const int w = threadIdx.x >> 6;     // wave in block
    const int i = (w << 2) + (l >> 4);  // row within tile (0..15), fixed/lane
    const int r = (tr << 4) + i;        // output row

    const float sl = 0.011f * sign_l[r];
    const float4* srp = (const float4*)sign_r + (size_t)tc0 * 4;
    float4v* op = (float4v*)(out + (size_t)r * 8192 + (size_t)tc0 * 16);

    const int base_f = l & 15;
#pragma unroll
    for (int s = 0; s < 4; ++s) {
        const int f = base_f + (s << 4); // float4 index in block's 256-col span
        const int j = f >> 2;            // tile within block (0..15)
        const int q = f & 3;             // float4 quad within tile row (0..3)
        // two walk steps for output cols [4q, 4q+3] of tile j, row i
        const int2 wpair = wlds2[j * 64 + i * 4 + q];
        const float2 v0 = lut2[wpair.x];
        const float2 v1 = lut2[wpair.y];
        const float4 sr = srp[f];
        float4v o;
        o.x = v0.x * (sl * sr.x);
        o.y = v0.y * (sl * sr.y);
        o.z = v1.x * (sl * sr.z);
        o.w = v1.y * (sl * sr.w);
        __builtin_nontemporal_store(o, op + f);
    }
}

extern "C" void kernel_launch(void* const* d_in, const int* in_sizes, int n_in,
                              void* d_out, int out_size, void* d_ws, size_t ws_size,
                              hipStream_t stream) {
    const int*   walks  = (const int*)d_in[0];
    const float* lut    = (const float*)d_in[1];
    const float* sign_l = (const float*)d_in[2];
    const float* sign_r = (const float*)d_in[3];
    float* out = (float*)d_out;

    // 262144 tiles / 16 tiles-per-block = 16384 blocks x 256 threads
    trellis_dequant<<<16384, 256, 0, stream>>>(walks, lut, sign_l, sign_r, out);
}

// Round 3
// 428.606 us; speedup vs baseline: 1.1478x; 1.0061x over previous
//
#include <hip/hip_runtime.h>

// Trellis-walk LUT dequant: out[r][c] = 0.011 * sign_l[r] * sign_r[c] *
//   lut[ walks[(r/16)*512 + c/16][ ((r%16)*16 + (c%16)) >> 1 ] ][ c & 1 ]
//
// R3 restructure (TA-transaction-bound): LDS-staged walks (kills 2x
// over-fetch), lane-interleaved float4 outputs (full-line stores), LDS-fed
// walk indices. Verified: 431 us bench (~132 us/dispatch), absmax 0.
//
// R5: batch the memory phases. R3's VGPR_Count=28 proves the compiler
// compiled the s-loop as serial load->gather->store chains (4 dependent
// ~500-cyc chains per thread). Restructure so all 4 ds_read_b64 issue,
// then all 8 LUT gathers, then compute, then all 4 stores; sign_l/sign_r
// loads hoisted before __syncthreads (independent of LDS). Target: hide
// gather latency behind MLP, approach the ~80-90 us L2/HBM floor.
//
// Device layout facts (established R0-R2):
//   - walks is INT32 on device; out is FLOAT32.

typedef int   int4v   __attribute__((ext_vector_type(4)));
typedef float float4v __attribute__((ext_vector_type(4)));

__global__ __launch_bounds__(256) void trellis_dequant(
    const int* __restrict__ walks,      // (262144, 128) int32, values < 2^16
    const float* __restrict__ lut,      // (65536, 2)
    const float* __restrict__ sign_l,   // (8192,)
    const float* __restrict__ sign_r,   // (8192,)
    float* __restrict__ out)            // (8192, 8192) float32
{
    __shared__ int4v wlds4[512];        // 16 tiles x 128 ints = 8 KB

    const int b   = blockIdx.x;
    const int T0  = b << 4;             // first linear tile of this block
    const int tr  = T0 >> 9;            // tile row
    const int tc0 = T0 & 511;           // first tile col

    // ---- Phase 1: coalesced stage of 16 tiles' walks into LDS ----
    const int4v* gw = (const int4v*)(walks + (size_t)T0 * 128);
    const int t = threadIdx.x;
    wlds4[t]       = __builtin_nontemporal_load(gw + t);
    wlds4[t + 256] = __builtin_nontemporal_load(gw + t + 256);

    // ---- Sign loads: independent of LDS, issue before the barrier ----
    const int l = t & 63;               // lane
    const int w = t >> 6;               // wave in block
    const int i = (w << 2) + (l >> 4);  // row within tile (0..15), fixed/lane
    const int r = (tr << 4) + i;        // output row
    const int base_f = l & 15;          // this thread's float4 slot (0..15)

    const float sl = 0.011f * sign_l[r];
    const float4* srp = (const float4*)sign_r + (size_t)tc0 * 4;
    float4 sr0 = srp[base_f];
    float4 sr1 = srp[base_f + 16];
    float4 sr2 = srp[base_f + 32];
    float4 sr3 = srp[base_f + 48];

    __syncthreads();

    // ---- Phase 2: batched LDS reads -> batched gathers -> stores ----
    const int2*   wlds2 = (const int2*)wlds4;
    const float2* lut2  = (const float2*)lut;

    const int j0    = base_f >> 2;      // first tile this thread touches
    const int q     = base_f & 3;       // float4 quad within tile row
    const int lbase = i * 4 + q;

    // all 4 walk-index pairs (ds_read_b64 x4, 2KB stride)
    const int2 wp0 = wlds2[(j0     ) * 64 + lbase];
    const int2 wp1 = wlds2[(j0 +  4) * 64 + lbase];
    const int2 wp2 = wlds2[(j0 +  8) * 64 + lbase];
    const int2 wp3 = wlds2[(j0 + 12) * 64 + lbase];

    // all 8 LUT gathers in flight together
    const float2 v0 = lut2[wp0.x];
    const float2 v1 = lut2[wp0.y];
    const float2 v2 = lut2[wp1.x];
    const float2 v3 = lut2[wp1.y];
    const float2 v4 = lut2[wp2.x];
    const float2 v5 = lut2[wp2.y];
    const float2 v6 = lut2[wp3.x];
    const float2 v7 = lut2[wp3.y];

    float4v o0, o1, o2, o3;
    o0.x = v0.x * (sl * sr0.x);
    o0.y = v0.y * (sl * sr0.y);
    o0.z = v1.x * (sl * sr0.z);
    o0.w = v1.y * (sl * sr0.w);
    o1.x = v2.x * (sl * sr1.x);
    o1.y = v2.y * (sl * sr1.y);
    o1.z = v3.x * (sl * sr1.z);
    o1.w = v3.y * (sl * sr1.w);
    o2.x = v4.x * (sl * sr2.x);
    o2.y = v4.y * (sl * sr2.y);
    o2.z = v5.x * (sl * sr2.z);
    o2.w = v5.y * (sl * sr2.w);
    o3.x = v6.x * (sl * sr3.x);
    o3.y = v6.y * (sl * sr3.y);
    o3.z = v7.x * (sl * sr3.z);
    o3.w = v7.y * (sl * sr3.w);

    float4v* op = (float4v*)(out + (size_t)r * 8192 + (size_t)tc0 * 16);
    __builtin_nontemporal_store(o0, op + base_f);
    __builtin_nontemporal_store(o1, op + base_f + 16);
    __builtin_nontemporal_store(o2, op + base_f + 32);
    __builtin_nontemporal_store(o3, op + base_f + 48);
}

extern "C" void kernel_launch(void* const* d_in, const int* in_sizes, int n_in,
                              void* d_out, int out_size, void* d_ws, size_t ws_size,
                              hipStream_t stream) {
    const int*   walks  = (const int*)d_in[0];
    const float* lut    = (const float*)d_in[1];
    const float* sign_l = (const float*)d_in[2];
    const float* sign_r = (const float*)d_in[3];
    float* out = (float*)d_out;

    // 262144 tiles / 16 tiles-per-block = 16384 blocks x 256 threads
    trellis_dequant<<<16384, 256, 0, stream>>>(walks, lut, sign_l, sign_r, out);
}